// Round 1
// baseline (1461.437 us; speedup 1.0000x reference)
//
#include <hip/hip_runtime.h>
#include <hip/hip_bf16.h>
#include <math.h>

// Problem constants
#define BSZ      512
#define IN_DIM   1024
#define OUT_DIM  2048
#define M_AND    5
#define LAM      1e-4f
#define TOL      1e-5f
#define MAX_ITER 50

// ---------------- workspace layout (in floats) ----------------
// W    : [2048][2048]      (= B^T - B - A^T A)
// bias : [512][2048]
// F    : [512][5][2048]
// G    : [512][5][2048]    (= F - Z, maintained directly)
// z_cur: [512][2048]       (latest z_new)
// red  : [64][2]           per-iteration {num2, den2} accumulators
// ctr  : [64] uint         per-iteration block-completion counters
// flag : int               converged flag
static constexpr size_t W_OFF    = 0;
static constexpr size_t BIAS_OFF = W_OFF    + (size_t)OUT_DIM * OUT_DIM;
static constexpr size_t F_OFF    = BIAS_OFF + (size_t)BSZ * OUT_DIM;
static constexpr size_t G_OFF    = F_OFF    + (size_t)BSZ * M_AND * OUT_DIM;
static constexpr size_t Z_OFF    = G_OFF    + (size_t)BSZ * M_AND * OUT_DIM;
static constexpr size_t RED_OFF  = Z_OFF    + (size_t)BSZ * OUT_DIM;
static constexpr size_t CTR_OFF  = RED_OFF  + 128;
static constexpr size_t FLAG_OFF = CTR_OFF  + 64;
static constexpr size_t WS_FLOATS = FLAG_OFF + 16;

// =================================================================
// W = B^T - B - A^T A       (A, B row-major 2048x2048)
// C[r][c] = B[c][r] - B[r][c] - sum_k A[k][r]*A[k][c]
// 64x64 tile, BK=32, 256 threads, 4x4 per thread
// =================================================================
__global__ __launch_bounds__(256)
void w_gemm(const float* __restrict__ A, const float* __restrict__ B,
            float* __restrict__ Wout)
{
    constexpr int BK = 32, PAD = 72;
    __shared__ float Ais[BK][PAD];
    __shared__ float Ajs[BK][PAD];
    const int tid = threadIdx.x;
    const int tx = tid & 15, ty = tid >> 4;
    const int row0 = blockIdx.y * 64, col0 = blockIdx.x * 64;
    const int ak = tid >> 3, ac = (tid & 7) * 8;   // stage: row ak of K-tile, 8 cols

    float acc[4][4] = {};
    for (int kk = 0; kk < OUT_DIM; kk += BK) {
        float4 a0 = *(const float4*)&A[(size_t)(kk + ak) * OUT_DIM + row0 + ac];
        float4 a1 = *(const float4*)&A[(size_t)(kk + ak) * OUT_DIM + row0 + ac + 4];
        float4 b0 = *(const float4*)&A[(size_t)(kk + ak) * OUT_DIM + col0 + ac];
        float4 b1 = *(const float4*)&A[(size_t)(kk + ak) * OUT_DIM + col0 + ac + 4];
        __syncthreads();
        *(float4*)&Ais[ak][ac]     = a0;
        *(float4*)&Ais[ak][ac + 4] = a1;
        *(float4*)&Ajs[ak][ac]     = b0;
        *(float4*)&Ajs[ak][ac + 4] = b1;
        __syncthreads();
        #pragma unroll
        for (int k = 0; k < BK; ++k) {
            const float4 av = *(const float4*)&Ais[k][ty * 4];
            const float4 bv = *(const float4*)&Ajs[k][tx * 4];
            const float aa[4] = {av.x, av.y, av.z, av.w};
            const float bb[4] = {bv.x, bv.y, bv.z, bv.w};
            #pragma unroll
            for (int i = 0; i < 4; ++i)
                #pragma unroll
                for (int j = 0; j < 4; ++j)
                    acc[i][j] += aa[i] * bb[j];
        }
    }
    #pragma unroll
    for (int i = 0; i < 4; ++i) {
        const int r = row0 + ty * 4 + i;
        #pragma unroll
        for (int j = 0; j < 4; ++j) {
            const int c = col0 + tx * 4 + j;
            Wout[(size_t)r * OUT_DIM + c] =
                B[(size_t)c * OUT_DIM + r] - B[(size_t)r * OUT_DIM + c] - acc[i][j];
        }
    }
}

// =================================================================
// bias = x @ U_W^T + U_b    (x 512x1024, U_W 2048x1024)
// C[b][o] = sum_k x[b][k]*U_W[o][k] + U_b[o]
// =================================================================
__global__ __launch_bounds__(256)
void bias_gemm(const float* __restrict__ x, const float* __restrict__ UW,
               const float* __restrict__ Ub, float* __restrict__ bias)
{
    constexpr int BK = 32, PAD = 72;
    __shared__ float Xs[BK][PAD];
    __shared__ float Us[BK][PAD];
    const int tid = threadIdx.x;
    const int tx = tid & 15, ty = tid >> 4;
    const int row0 = blockIdx.y * 64, col0 = blockIdx.x * 64;
    const int lr = tid >> 2, lkc = (tid & 3) * 8;   // stage: 1 row, 8 consecutive k

    float acc[4][4] = {};
    for (int kk = 0; kk < IN_DIM; kk += BK) {
        float4 xa = *(const float4*)&x[(size_t)(row0 + lr) * IN_DIM + kk + lkc];
        float4 xb = *(const float4*)&x[(size_t)(row0 + lr) * IN_DIM + kk + lkc + 4];
        float4 ua = *(const float4*)&UW[(size_t)(col0 + lr) * IN_DIM + kk + lkc];
        float4 ub = *(const float4*)&UW[(size_t)(col0 + lr) * IN_DIM + kk + lkc + 4];
        __syncthreads();
        const float xv[8] = {xa.x, xa.y, xa.z, xa.w, xb.x, xb.y, xb.z, xb.w};
        const float uv[8] = {ua.x, ua.y, ua.z, ua.w, ub.x, ub.y, ub.z, ub.w};
        #pragma unroll
        for (int q = 0; q < 8; ++q) { Xs[lkc + q][lr] = xv[q]; Us[lkc + q][lr] = uv[q]; }
        __syncthreads();
        #pragma unroll
        for (int k = 0; k < BK; ++k) {
            const float4 av = *(const float4*)&Xs[k][ty * 4];
            const float4 bv = *(const float4*)&Us[k][tx * 4];
            const float aa[4] = {av.x, av.y, av.z, av.w};
            const float bb[4] = {bv.x, bv.y, bv.z, bv.w};
            #pragma unroll
            for (int i = 0; i < 4; ++i)
                #pragma unroll
                for (int j = 0; j < 4; ++j)
                    acc[i][j] += aa[i] * bb[j];
        }
    }
    #pragma unroll
    for (int i = 0; i < 4; ++i) {
        const int r = row0 + ty * 4 + i;
        #pragma unroll
        for (int j = 0; j < 4; ++j) {
            const int c = col0 + tx * 4 + j;
            bias[(size_t)r * OUT_DIM + c] = acc[i][j] + Ub[c];
        }
    }
}

// =================================================================
// f0 = relu(bias); F[:,0]=f0; G[:,0]=f0 (Z[:,0]=0); z_cur=f0
// =================================================================
__global__ __launch_bounds__(256)
void f0_kernel(const float* __restrict__ bias, float* __restrict__ F,
               float* __restrict__ G, float* __restrict__ zc)
{
    const int idx = blockIdx.x * 256 + threadIdx.x;        // < 512*2048
    const int b = idx >> 11, d = idx & (OUT_DIM - 1);
    const float v = fmaxf(bias[idx], 0.f);
    F[((size_t)b * M_AND + 0) * OUT_DIM + d] = v;
    G[((size_t)b * M_AND + 0) * OUT_DIM + d] = v;
    zc[idx] = v;
}

// =================================================================
// Iteration GEMM + fused epilogue:
//   t  = z_cur @ W ; zo = relu(t + bias)
//   F[:,slot] = zo ; G[:,slot] = zo - z_cur ; out = zo
//   DO_ERR: accumulate ||zo - z||^2, ||zo||^2 -> last block sets flag
// =================================================================
template<bool DO_ERR>
__global__ __launch_bounds__(256)
void iter_gemm(const float* __restrict__ zin, const float* __restrict__ Wm,
               const float* __restrict__ bias, float* __restrict__ F,
               float* __restrict__ G, float* __restrict__ out,
               float* red, unsigned int* ctr, int* flag, int slot, int it)
{
    if (((volatile int*)flag)[0]) return;
    constexpr int BK = 32, PAD = 72;
    __shared__ float Zs[BK][PAD];
    __shared__ float Ws[BK][PAD];
    const int tid = threadIdx.x;
    const int tx = tid & 15, ty = tid >> 4;
    const int row0 = blockIdx.y * 64, col0 = blockIdx.x * 64;
    const int zr = tid >> 2, zkc = (tid & 3) * 8;   // z stage (transpose into LDS)
    const int wk = tid >> 3, wc = (tid & 7) * 8;    // W stage (natural layout)

    float acc[4][4] = {};
    for (int kk = 0; kk < OUT_DIM; kk += BK) {
        float4 za = *(const float4*)&zin[(size_t)(row0 + zr) * OUT_DIM + kk + zkc];
        float4 zb = *(const float4*)&zin[(size_t)(row0 + zr) * OUT_DIM + kk + zkc + 4];
        float4 wa = *(const float4*)&Wm[(size_t)(kk + wk) * OUT_DIM + col0 + wc];
        float4 wb = *(const float4*)&Wm[(size_t)(kk + wk) * OUT_DIM + col0 + wc + 4];
        __syncthreads();
        const float zv[8] = {za.x, za.y, za.z, za.w, zb.x, zb.y, zb.z, zb.w};
        #pragma unroll
        for (int q = 0; q < 8; ++q) Zs[zkc + q][zr] = zv[q];
        *(float4*)&Ws[wk][wc]     = wa;
        *(float4*)&Ws[wk][wc + 4] = wb;
        __syncthreads();
        #pragma unroll
        for (int k = 0; k < BK; ++k) {
            const float4 av = *(const float4*)&Zs[k][ty * 4];
            const float4 bv = *(const float4*)&Ws[k][tx * 4];
            const float aa[4] = {av.x, av.y, av.z, av.w};
            const float bb[4] = {bv.x, bv.y, bv.z, bv.w};
            #pragma unroll
            for (int i = 0; i < 4; ++i)
                #pragma unroll
                for (int j = 0; j < 4; ++j)
                    acc[i][j] += aa[i] * bb[j];
        }
    }

    float lnum = 0.f, lden = 0.f;
    #pragma unroll
    for (int i = 0; i < 4; ++i) {
        const int r = row0 + ty * 4 + i;
        #pragma unroll
        for (int j = 0; j < 4; ++j) {
            const int c = col0 + tx * 4 + j;
            float v = acc[i][j] + bias[(size_t)r * OUT_DIM + c];
            v = fmaxf(v, 0.f);
            const float zc = zin[(size_t)r * OUT_DIM + c];
            const float gg = v - zc;
            F[((size_t)r * M_AND + slot) * OUT_DIM + c] = v;
            G[((size_t)r * M_AND + slot) * OUT_DIM + c] = gg;
            out[(size_t)r * OUT_DIM + c] = v;
            if (DO_ERR) { lnum += gg * gg; lden += v * v; }
        }
    }

    if (DO_ERR) {
        #pragma unroll
        for (int off = 32; off; off >>= 1) {
            lnum += __shfl_down(lnum, off);
            lden += __shfl_down(lden, off);
        }
        __shared__ float swn[4], swd[4];
        if ((tid & 63) == 0) { swn[tid >> 6] = lnum; swd[tid >> 6] = lden; }
        __syncthreads();
        if (tid == 0) {
            atomicAdd(&red[2 * it],     swn[0] + swn[1] + swn[2] + swn[3]);
            atomicAdd(&red[2 * it + 1], swd[0] + swd[1] + swd[2] + swd[3]);
            __threadfence();
            const unsigned int done = atomicAdd(&ctr[it], 1u);
            if (done == gridDim.x * gridDim.y - 1) {
                const float num2 = ((volatile float*)red)[2 * it];
                const float den2 = ((volatile float*)red)[2 * it + 1];
                if (sqrtf(num2) <= TOL * (1e-6f + sqrtf(den2)))
                    ((volatile int*)flag)[0] = 1;
            }
        }
    }
}

// =================================================================
// Anderson coefficients + z_new.  One block per batch row.
//   n = min(5, it); M = GGt/(||GGt||_F + 1e-6) + LAM*I (active nxn)
//   solve M u = 1 (Cholesky), alpha = u / sum(u)
//   z_cur = sum_m alpha[m] * F[:,m]
// =================================================================
__global__ __launch_bounds__(256)
void anderson_kernel(const float* __restrict__ F, const float* __restrict__ G,
                     float* __restrict__ zc, int* flag, int it)
{
    if (((volatile int*)flag)[0]) return;
    const int b = blockIdx.x;
    const int tid = threadIdx.x;
    const int n = (it < M_AND) ? it : M_AND;
    const float* Gb = G + (size_t)b * M_AND * OUT_DIM;
    const float* Fb = F + (size_t)b * M_AND * OUT_DIM;

    // per-thread slices of the G rows (8 elements each, stride 256)
    float g[M_AND][8];
    #pragma unroll
    for (int m = 0; m < M_AND; ++m) {
        if (m < n) {
            #pragma unroll
            for (int q = 0; q < 8; ++q)
                g[m][q] = Gb[(size_t)m * OUT_DIM + q * 256 + tid];
        } else {
            #pragma unroll
            for (int q = 0; q < 8; ++q) g[m][q] = 0.f;
        }
    }

    // 15 upper-triangular pair dots
    float dots[15];
    {
        int p = 0;
        #pragma unroll
        for (int i = 0; i < M_AND; ++i)
            #pragma unroll
            for (int j = i; j < M_AND; ++j) {
                float s = 0.f;
                #pragma unroll
                for (int q = 0; q < 8; ++q) s += g[i][q] * g[j][q];
                dots[p++] = s;
            }
    }

    __shared__ float sred[15][4];
    #pragma unroll
    for (int p = 0; p < 15; ++p) {
        float v = dots[p];
        #pragma unroll
        for (int off = 32; off; off >>= 1) v += __shfl_down(v, off);
        if ((tid & 63) == 0) sred[p][tid >> 6] = v;
    }
    __syncthreads();

    __shared__ float s_alpha[M_AND];
    if (tid == 0) {
        float GGm[M_AND][M_AND];
        int p = 0;
        for (int i = 0; i < M_AND; ++i)
            for (int j = i; j < M_AND; ++j) {
                const float v = sred[p][0] + sred[p][1] + sred[p][2] + sred[p][3];
                GGm[i][j] = v; GGm[j][i] = v; ++p;
            }
        float fro = 0.f;
        for (int i = 0; i < M_AND; ++i)
            for (int j = 0; j < M_AND; ++j) fro += GGm[i][j] * GGm[i][j];
        const float inv = 1.f / (sqrtf(fro) + 1e-6f);

        float Mm[M_AND][M_AND];
        for (int i = 0; i < n; ++i)
            for (int j = 0; j < n; ++j)
                Mm[i][j] = GGm[i][j] * inv + (i == j ? LAM : 0.f);

        // Cholesky M = L L^T
        float L[M_AND][M_AND];
        for (int i = 0; i < n; ++i)
            for (int j = 0; j <= i; ++j) {
                float s = Mm[i][j];
                for (int k = 0; k < j; ++k) s -= L[i][k] * L[j][k];
                L[i][j] = (i == j) ? sqrtf(fmaxf(s, 1e-20f)) : s / L[j][j];
            }
        float y[M_AND], u[M_AND];
        for (int i = 0; i < n; ++i) {
            float s = 1.f;
            for (int k = 0; k < i; ++k) s -= L[i][k] * y[k];
            y[i] = s / L[i][i];
        }
        for (int i = n - 1; i >= 0; --i) {
            float s = y[i];
            for (int k = i + 1; k < n; ++k) s -= L[k][i] * u[k];
            u[i] = s / L[i][i];
        }
        float su = 0.f;
        for (int i = 0; i < n; ++i) su += u[i];
        const float isu = 1.f / su;
        for (int m = 0; m < M_AND; ++m) s_alpha[m] = (m < n) ? u[m] * isu : 0.f;
    }
    __syncthreads();

    #pragma unroll
    for (int q = 0; q < 8; ++q) {
        float z = 0.f;
        for (int m = 0; m < M_AND; ++m)
            if (m < n) z += s_alpha[m] * Fb[(size_t)m * OUT_DIM + q * 256 + tid];
        zc[(size_t)b * OUT_DIM + q * 256 + tid] = z;
    }
}

// =================================================================
extern "C" void kernel_launch(void* const* d_in, const int* in_sizes, int n_in,
                              void* d_out, int out_size, void* d_ws, size_t ws_size,
                              hipStream_t stream)
{
    const float* x  = (const float*)d_in[0];
    const float* A  = (const float*)d_in[1];
    const float* B  = (const float*)d_in[2];
    const float* UW = (const float*)d_in[3];
    const float* Ub = (const float*)d_in[4];
    float* out = (float*)d_out;
    float* ws  = (float*)d_ws;

    float*        Wm   = ws + W_OFF;
    float*        bias = ws + BIAS_OFF;
    float*        F    = ws + F_OFF;
    float*        G    = ws + G_OFF;
    float*        zc   = ws + Z_OFF;
    float*        red  = ws + RED_OFF;
    unsigned int* ctr  = (unsigned int*)(ws + CTR_OFF);
    int*          flag = (int*)(ws + FLAG_OFF);

    // zero the control region (red, ctr, flag) every call
    hipMemsetAsync(red, 0, (WS_FLOATS - RED_OFF) * sizeof(float), stream);

    // one-time (per call) precomputes
    w_gemm   <<<dim3(32, 32), 256, 0, stream>>>(A, B, Wm);
    bias_gemm<<<dim3(32, 8),  256, 0, stream>>>(x, UW, Ub, bias);

    // f0 = relu(bias): F0, G0, z_cur
    f0_kernel<<<dim3(BSZ * OUT_DIM / 256), 256, 0, stream>>>(bias, F, G, zc);

    // f1 = relu(f0 @ W + bias): F1, G1 = f1 - f0  (no err)
    iter_gemm<false><<<dim3(32, 8), 256, 0, stream>>>(zc, Wm, bias, F, G, out,
                                                      nullptr, nullptr, flag, 1, 0);

    // Anderson loop, it = 2 .. 49, device-side early exit via flag
    for (int it = 2; it < MAX_ITER; ++it) {
        anderson_kernel<<<dim3(BSZ), 256, 0, stream>>>(F, G, zc, flag, it);
        iter_gemm<true><<<dim3(32, 8), 256, 0, stream>>>(zc, Wm, bias, F, G, out,
                                                         red, ctr, flag, it % 5, it);
    }
}

// Round 2
// 768.715 us; speedup vs baseline: 1.9011x; 1.9011x over previous
//
#include <hip/hip_runtime.h>
#include <hip/hip_bf16.h>
#include <math.h>

#define BSZ      512
#define IN_DIM   1024
#define OUT_DIM  2048
#define M_AND    5
#define LAM      1e-4f
#define TOL      1e-5f
#define MAX_ITER 50

typedef __bf16 bf16x8 __attribute__((ext_vector_type(8)));
typedef float  f32x4  __attribute__((ext_vector_type(4)));
typedef __hip_bfloat16 bf16;

#define GAS __attribute__((address_space(1)))
#define LAS __attribute__((address_space(3)))

union BU { bf16 b; unsigned short u; };

// ---------------- workspace layout (byte offsets) ----------------
static constexpr size_t BIAS_B = 0;                                          // fp32 [512][2048]
static constexpr size_t F_B    = BIAS_B + (size_t)BSZ * OUT_DIM * 4;         // fp32 [512][5][2048]
static constexpr size_t G_B    = F_B    + (size_t)BSZ * M_AND * OUT_DIM * 4; // fp32 [512][5][2048]
static constexpr size_t ZH_B   = G_B    + (size_t)BSZ * M_AND * OUT_DIM * 4; // bf16 [512][2048]
static constexpr size_t ZL_B   = ZH_B   + (size_t)BSZ * OUT_DIM * 2;         // bf16 [512][2048]
static constexpr size_t AT_B   = ZL_B   + (size_t)BSZ * OUT_DIM * 2;         // bf16 [2048][2048]  A^T
static constexpr size_t WT_B   = AT_B   + (size_t)OUT_DIM * OUT_DIM * 2;     // bf16 [2048][2048]  W^T
static constexpr size_t RED_B  = WT_B   + (size_t)OUT_DIM * OUT_DIM * 2;     // fp32 [128]
static constexpr size_t CTR_B  = RED_B  + 512;                               // u32  [64]
static constexpr size_t FLAG_B = CTR_B  + 256;                               // int

// =================================================================
// Staging: global -> LDS, 16B/lane, tile pitch 128B (64 bf16 cols),
// T2 XOR swizzle applied by PRE-SWIZZLING the global source address
// (rule #21: linear LDS dest + inverse-swz source + swz on read).
// =================================================================
template<int ROUNDS>
__device__ __forceinline__ void stage_tile(const bf16* __restrict__ g0, bf16* l0, int tid)
{
    #pragma unroll
    for (int q = 0; q < ROUNDS; ++q) {
        const int D   = q * 4096 + tid * 16;       // linear LDS byte
        const int r   = D >> 7;                    // tile row
        const int cb  = D & 127;                   // col byte
        const int scb = cb ^ ((r & 7) << 4);       // swizzled source col byte
        const char* gsrc = (const char*)g0 + (size_t)r * (OUT_DIM * 2) + scb;
        char* ldst = (char*)l0 + q * 4096 + (tid >> 6) * 1024;   // wave-uniform base
        __builtin_amdgcn_global_load_lds((const GAS void*)gsrc, (LAS void*)ldst, 16, 0, 0);
    }
}

// swizzled fragment read: 8 contiguous bf16 (k) at tile row `row`
__device__ __forceinline__ bf16x8 read_frag(const bf16* tile, int row, int cb)
{
    return *(const bf16x8*)((const char*)tile + row * 128 + (cb ^ ((row & 7) << 4)));
}

// =================================================================
// prep_at: At[c][k] = bf16(A[k][c])   (A fp32 row-major 2048x2048)
// =================================================================
__global__ __launch_bounds__(256)
void prep_at(const float* __restrict__ A, bf16* __restrict__ At)
{
    __shared__ float t[64][65];
    const int tid = threadIdx.x;
    const int k0 = blockIdx.y * 64, c0 = blockIdx.x * 64;
    const int cc = tid & 63, rr = tid >> 6;
    #pragma unroll
    for (int q = 0; q < 16; ++q)
        t[rr + 4 * q][cc] = A[(size_t)(k0 + rr + 4 * q) * OUT_DIM + c0 + cc];
    __syncthreads();
    #pragma unroll
    for (int q = 0; q < 16; ++q)
        At[(size_t)(c0 + rr + 4 * q) * OUT_DIM + k0 + cc] = __float2bfloat16(t[cc][rr + 4 * q]);
}

// =================================================================
// w_mfma: S = A^T A via MFMA (both operands from At), then
//   Wt[c][r] = bf16( B[c][r] - B[r][c] - S[r][c] )
// 128x128 tile, 4 waves (2x2), BK=64, double-buffered.
// =================================================================
__global__ __launch_bounds__(256)
void w_mfma(const bf16* __restrict__ At, const float* __restrict__ Bm, bf16* __restrict__ Wt)
{
    __shared__ __align__(16) bf16 lds[2][2][128 * 64];
    const int tid = threadIdx.x;
    const int lane = tid & 63, wid = tid >> 6;
    const int wy = wid >> 1, wx = wid & 1;
    const int r0 = blockIdx.y * 128, c0 = blockIdx.x * 128;

    f32x4 acc[4][4];
    #pragma unroll
    for (int i = 0; i < 4; ++i)
        #pragma unroll
        for (int j = 0; j < 4; ++j) acc[i][j] = 0;

    stage_tile<4>(At + (size_t)r0 * OUT_DIM, lds[0][0], tid);
    stage_tile<4>(At + (size_t)c0 * OUT_DIM, lds[0][1], tid);
    __syncthreads();
    int cur = 0;
    for (int t = 0; t < 32; ++t) {
        if (t + 1 < 32) {
            const int kk = (t + 1) * 64;
            stage_tile<4>(At + (size_t)r0 * OUT_DIM + kk, lds[cur ^ 1][0], tid);
            stage_tile<4>(At + (size_t)c0 * OUT_DIM + kk, lds[cur ^ 1][1], tid);
        }
        const bf16* Ta = lds[cur][0];
        const bf16* Tb = lds[cur][1];
        #pragma unroll
        for (int kf = 0; kf < 2; ++kf) {
            const int cb = kf * 64 + (lane >> 4) * 16;
            bf16x8 bfr[4];
            #pragma unroll
            for (int nj = 0; nj < 4; ++nj)
                bfr[nj] = read_frag(Tb, wx * 64 + nj * 16 + (lane & 15), cb);
            #pragma unroll
            for (int mi = 0; mi < 4; ++mi) {
                bf16x8 afr = read_frag(Ta, wy * 64 + mi * 16 + (lane & 15), cb);
                #pragma unroll
                for (int nj = 0; nj < 4; ++nj)
                    acc[mi][nj] = __builtin_amdgcn_mfma_f32_16x16x32_bf16(afr, bfr[nj], acc[mi][nj], 0, 0, 0);
            }
        }
        __syncthreads();
        cur ^= 1;
    }

    #pragma unroll
    for (int mi = 0; mi < 4; ++mi) {
        const int rb = r0 + wy * 64 + mi * 16 + (lane >> 4) * 4;
        #pragma unroll
        for (int nj = 0; nj < 4; ++nj) {
            const int c = c0 + wx * 64 + nj * 16 + (lane & 15);
            const float4 bc = *(const float4*)&Bm[(size_t)c * OUT_DIM + rb];
            const float bcv[4] = {bc.x, bc.y, bc.z, bc.w};
            union { short4 s4; unsigned short u[4]; } p;
            #pragma unroll
            for (int g = 0; g < 4; ++g) {
                const float w = bcv[g] - Bm[(size_t)(rb + g) * OUT_DIM + c] - acc[mi][nj][g];
                BU t2; t2.b = __float2bfloat16(w);
                p.u[g] = t2.u;
            }
            *(short4*)((char*)Wt + ((size_t)c * OUT_DIM + rb) * 2) = p.s4;
        }
    }
}

// =================================================================
// bias = x @ U_W^T + U_b   (fp32 VALU, unchanged from r1 — runs once)
// =================================================================
__global__ __launch_bounds__(256)
void bias_gemm(const float* __restrict__ x, const float* __restrict__ UW,
               const float* __restrict__ Ub, float* __restrict__ bias)
{
    constexpr int BK = 32, PAD = 72;
    __shared__ float Xs[BK][PAD];
    __shared__ float Us[BK][PAD];
    const int tid = threadIdx.x;
    const int tx = tid & 15, ty = tid >> 4;
    const int row0 = blockIdx.y * 64, col0 = blockIdx.x * 64;
    const int lr = tid >> 2, lkc = (tid & 3) * 8;

    float acc[4][4] = {};
    for (int kk = 0; kk < IN_DIM; kk += BK) {
        float4 xa = *(const float4*)&x[(size_t)(row0 + lr) * IN_DIM + kk + lkc];
        float4 xb = *(const float4*)&x[(size_t)(row0 + lr) * IN_DIM + kk + lkc + 4];
        float4 ua = *(const float4*)&UW[(size_t)(col0 + lr) * IN_DIM + kk + lkc];
        float4 ub = *(const float4*)&UW[(size_t)(col0 + lr) * IN_DIM + kk + lkc + 4];
        __syncthreads();
        const float xv[8] = {xa.x, xa.y, xa.z, xa.w, xb.x, xb.y, xb.z, xb.w};
        const float uv[8] = {ua.x, ua.y, ua.z, ua.w, ub.x, ub.y, ub.z, ub.w};
        #pragma unroll
        for (int q = 0; q < 8; ++q) { Xs[lkc + q][lr] = xv[q]; Us[lkc + q][lr] = uv[q]; }
        __syncthreads();
        #pragma unroll
        for (int k = 0; k < BK; ++k) {
            const float4 av = *(const float4*)&Xs[k][ty * 4];
            const float4 bv = *(const float4*)&Us[k][tx * 4];
            const float aa[4] = {av.x, av.y, av.z, av.w};
            const float bb[4] = {bv.x, bv.y, bv.z, bv.w};
            #pragma unroll
            for (int i = 0; i < 4; ++i)
                #pragma unroll
                for (int j = 0; j < 4; ++j)
                    acc[i][j] += aa[i] * bb[j];
        }
    }
    #pragma unroll
    for (int i = 0; i < 4; ++i) {
        const int r = row0 + ty * 4 + i;
        #pragma unroll
        for (int j = 0; j < 4; ++j) {
            const int c = col0 + tx * 4 + j;
            bias[(size_t)r * OUT_DIM + c] = acc[i][j] + Ub[c];
        }
    }
}

// =================================================================
// f0 = relu(bias); F0 = G0 = f0 (Z0 = 0); z -> (zh, zl) split
// =================================================================
__global__ __launch_bounds__(256)
void f0_kernel(const float* __restrict__ bias, float* __restrict__ F, float* __restrict__ G,
               bf16* __restrict__ zh, bf16* __restrict__ zl)
{
    const size_t i4 = ((size_t)blockIdx.x * 256 + threadIdx.x) * 4;
    const int b = (int)(i4 >> 11), d = (int)(i4 & 2047);
    const float4 v = *(const float4*)&bias[i4];
    const float vv[4] = {fmaxf(v.x, 0.f), fmaxf(v.y, 0.f), fmaxf(v.z, 0.f), fmaxf(v.w, 0.f)};
    float4 o; o.x = vv[0]; o.y = vv[1]; o.z = vv[2]; o.w = vv[3];
    *(float4*)&F[((size_t)b * M_AND + 0) * OUT_DIM + d] = o;
    *(float4*)&G[((size_t)b * M_AND + 0) * OUT_DIM + d] = o;
    union { short4 s4; unsigned short u[4]; } ph, pl;
    #pragma unroll
    for (int j = 0; j < 4; ++j) {
        BU h; h.b = __float2bfloat16(vv[j]);
        BU l; l.b = __float2bfloat16(vv[j] - __bfloat162float(h.b));
        ph.u[j] = h.u; pl.u[j] = l.u;
    }
    *(short4*)((char*)zh + i4 * 2) = ph.s4;
    *(short4*)((char*)zl + i4 * 2) = pl.s4;
}

// =================================================================
// iter_mfma: zo = relu((zh+zl) @ W + bias)  via 2 MFMA passes into
// the same accumulator (exact split-z).  Epilogue: F[slot]=zo,
// G[slot]=zo-(zh+zl), out=zo, optional convergence reduction.
// 64x64 tile, 256 blocks, 4 waves (2x2), BK=64, double-buffered.
// =================================================================
template<bool DO_ERR>
__global__ __launch_bounds__(256)
void iter_mfma(const bf16* __restrict__ zh, const bf16* __restrict__ zl,
               const bf16* __restrict__ Wt, const float* __restrict__ bias,
               float* __restrict__ F, float* __restrict__ G, float* __restrict__ out,
               float* red, unsigned int* ctr, int* flag, int slot, int it)
{
    if (((volatile int*)flag)[0]) return;
    __shared__ __align__(16) bf16 lds[2][3][64 * 64];
    const int tid = threadIdx.x;
    const int lane = tid & 63, wid = tid >> 6;
    const int wy = wid >> 1, wx = wid & 1;
    const int m0 = blockIdx.y * 64, n0 = blockIdx.x * 64;

    f32x4 acc[2][2];
    #pragma unroll
    for (int i = 0; i < 2; ++i)
        #pragma unroll
        for (int j = 0; j < 2; ++j) acc[i][j] = 0;

    stage_tile<2>(zh + (size_t)m0 * OUT_DIM, lds[0][0], tid);
    stage_tile<2>(zl + (size_t)m0 * OUT_DIM, lds[0][1], tid);
    stage_tile<2>(Wt + (size_t)n0 * OUT_DIM, lds[0][2], tid);
    __syncthreads();
    int cur = 0;
    for (int t = 0; t < 32; ++t) {
        if (t + 1 < 32) {
            const int kk = (t + 1) * 64;
            stage_tile<2>(zh + (size_t)m0 * OUT_DIM + kk, lds[cur ^ 1][0], tid);
            stage_tile<2>(zl + (size_t)m0 * OUT_DIM + kk, lds[cur ^ 1][1], tid);
            stage_tile<2>(Wt + (size_t)n0 * OUT_DIM + kk, lds[cur ^ 1][2], tid);
        }
        const bf16* Th = lds[cur][0];
        const bf16* Tl = lds[cur][1];
        const bf16* Tw = lds[cur][2];
        #pragma unroll
        for (int kf = 0; kf < 2; ++kf) {
            const int cb = kf * 64 + (lane >> 4) * 16;
            bf16x8 bfr[2];
            #pragma unroll
            for (int nj = 0; nj < 2; ++nj)
                bfr[nj] = read_frag(Tw, wx * 32 + nj * 16 + (lane & 15), cb);
            #pragma unroll
            for (int mi = 0; mi < 2; ++mi) {
                const int rrow = wy * 32 + mi * 16 + (lane & 15);
                bf16x8 ah = read_frag(Th, rrow, cb);
                bf16x8 al = read_frag(Tl, rrow, cb);
                #pragma unroll
                for (int nj = 0; nj < 2; ++nj) {
                    acc[mi][nj] = __builtin_amdgcn_mfma_f32_16x16x32_bf16(ah, bfr[nj], acc[mi][nj], 0, 0, 0);
                    acc[mi][nj] = __builtin_amdgcn_mfma_f32_16x16x32_bf16(al, bfr[nj], acc[mi][nj], 0, 0, 0);
                }
            }
        }
        __syncthreads();
        cur ^= 1;
    }

    float lnum = 0.f, lden = 0.f;
    #pragma unroll
    for (int mi = 0; mi < 2; ++mi) {
        const int mb = m0 + wy * 32 + mi * 16 + (lane >> 4) * 4;
        #pragma unroll
        for (int nj = 0; nj < 2; ++nj) {
            const int n = n0 + wx * 32 + nj * 16 + (lane & 15);
            #pragma unroll
            for (int g = 0; g < 4; ++g) {
                const int m = mb + g;
                const size_t idx = (size_t)m * OUT_DIM + n;
                float v = acc[mi][nj][g] + bias[idx];
                v = fmaxf(v, 0.f);
                const float zc = __bfloat162float(zh[idx]) + __bfloat162float(zl[idx]);
                const float gg = v - zc;
                F[((size_t)m * M_AND + slot) * OUT_DIM + n] = v;
                G[((size_t)m * M_AND + slot) * OUT_DIM + n] = gg;
                out[idx] = v;
                if (DO_ERR) { lnum += gg * gg; lden += v * v; }
            }
        }
    }

    if (DO_ERR) {
        #pragma unroll
        for (int off = 32; off; off >>= 1) {
            lnum += __shfl_down(lnum, off);
            lden += __shfl_down(lden, off);
        }
        __shared__ float swn[4], swd[4];
        if ((tid & 63) == 0) { swn[tid >> 6] = lnum; swd[tid >> 6] = lden; }
        __syncthreads();
        if (tid == 0) {
            atomicAdd(&red[2 * it],     swn[0] + swn[1] + swn[2] + swn[3]);
            atomicAdd(&red[2 * it + 1], swd[0] + swd[1] + swd[2] + swd[3]);
            __threadfence();
            const unsigned int done = atomicAdd(&ctr[it], 1u);
            if (done == gridDim.x * gridDim.y - 1) {
                const float num2 = ((volatile float*)red)[2 * it];
                const float den2 = ((volatile float*)red)[2 * it + 1];
                if (sqrtf(num2) <= TOL * (1e-6f + sqrtf(den2)))
                    ((volatile int*)flag)[0] = 1;
            }
        }
    }
}

// =================================================================
// Anderson: GGt (n<=5), normalize, +lam*I, Cholesky solve, alpha,
// z_new = sum alpha_m F[:,m]  -> (zh, zl) split.  One block/row.
// =================================================================
__global__ __launch_bounds__(256)
void anderson_kernel(const float* __restrict__ F, const float* __restrict__ G,
                     bf16* __restrict__ zh, bf16* __restrict__ zl, int* flag, int it)
{
    if (((volatile int*)flag)[0]) return;
    const int b = blockIdx.x;
    const int tid = threadIdx.x;
    const int n = (it < M_AND) ? it : M_AND;
    const float* Gb = G + (size_t)b * M_AND * OUT_DIM;
    const float* Fb = F + (size_t)b * M_AND * OUT_DIM;

    float g[M_AND][8];
    #pragma unroll
    for (int m = 0; m < M_AND; ++m) {
        if (m < n) {
            #pragma unroll
            for (int q = 0; q < 8; ++q)
                g[m][q] = Gb[(size_t)m * OUT_DIM + q * 256 + tid];
        } else {
            #pragma unroll
            for (int q = 0; q < 8; ++q) g[m][q] = 0.f;
        }
    }

    float dots[15];
    {
        int p = 0;
        #pragma unroll
        for (int i = 0; i < M_AND; ++i)
            #pragma unroll
            for (int j = i; j < M_AND; ++j) {
                float s = 0.f;
                #pragma unroll
                for (int q = 0; q < 8; ++q) s += g[i][q] * g[j][q];
                dots[p++] = s;
            }
    }

    __shared__ float sred[15][4];
    #pragma unroll
    for (int p = 0; p < 15; ++p) {
        float v = dots[p];
        #pragma unroll
        for (int off = 32; off; off >>= 1) v += __shfl_down(v, off);
        if ((tid & 63) == 0) sred[p][tid >> 6] = v;
    }
    __syncthreads();

    __shared__ float s_alpha[M_AND];
    if (tid == 0) {
        float GGm[M_AND][M_AND];
        int p = 0;
        for (int i = 0; i < M_AND; ++i)
            for (int j = i; j < M_AND; ++j) {
                const float v = sred[p][0] + sred[p][1] + sred[p][2] + sred[p][3];
                GGm[i][j] = v; GGm[j][i] = v; ++p;
            }
        float fro = 0.f;
        for (int i = 0; i < M_AND; ++i)
            for (int j = 0; j < M_AND; ++j) fro += GGm[i][j] * GGm[i][j];
        const float inv = 1.f / (sqrtf(fro) + 1e-6f);

        float Mm[M_AND][M_AND];
        for (int i = 0; i < n; ++i)
            for (int j = 0; j < n; ++j)
                Mm[i][j] = GGm[i][j] * inv + (i == j ? LAM : 0.f);

        float L[M_AND][M_AND];
        for (int i = 0; i < n; ++i)
            for (int j = 0; j <= i; ++j) {
                float s = Mm[i][j];
                for (int k = 0; k < j; ++k) s -= L[i][k] * L[j][k];
                L[i][j] = (i == j) ? sqrtf(fmaxf(s, 1e-20f)) : s / L[j][j];
            }
        float y[M_AND], u[M_AND];
        for (int i = 0; i < n; ++i) {
            float s = 1.f;
            for (int k = 0; k < i; ++k) s -= L[i][k] * y[k];
            y[i] = s / L[i][i];
        }
        for (int i = n - 1; i >= 0; --i) {
            float s = y[i];
            for (int k = i + 1; k < n; ++k) s -= L[k][i] * u[k];
            u[i] = s / L[i][i];
        }
        float su = 0.f;
        for (int i = 0; i < n; ++i) su += u[i];
        const float isu = 1.f / su;
        for (int m = 0; m < M_AND; ++m) s_alpha[m] = (m < n) ? u[m] * isu : 0.f;
    }
    __syncthreads();

    #pragma unroll
    for (int q = 0; q < 8; ++q) {
        float z = 0.f;
        for (int m = 0; m < M_AND; ++m)
            if (m < n) z += s_alpha[m] * Fb[(size_t)m * OUT_DIM + q * 256 + tid];
        const size_t idx = (size_t)b * OUT_DIM + q * 256 + tid;
        BU h; h.b = __float2bfloat16(z);
        BU l; l.b = __float2bfloat16(z - __bfloat162float(h.b));
        zh[idx] = h.b; zl[idx] = l.b;
    }
}

// =================================================================
extern "C" void kernel_launch(void* const* d_in, const int* in_sizes, int n_in,
                              void* d_out, int out_size, void* d_ws, size_t ws_size,
                              hipStream_t stream)
{
    const float* x  = (const float*)d_in[0];
    const float* A  = (const float*)d_in[1];
    const float* B  = (const float*)d_in[2];
    const float* UW = (const float*)d_in[3];
    const float* Ub = (const float*)d_in[4];
    float* out = (float*)d_out;
    char*  wsb = (char*)d_ws;

    float*        bias = (float*)(wsb + BIAS_B);
    float*        F    = (float*)(wsb + F_B);
    float*        G    = (float*)(wsb + G_B);
    bf16*         zh   = (bf16*)(wsb + ZH_B);
    bf16*         zl   = (bf16*)(wsb + ZL_B);
    bf16*         At   = (bf16*)(wsb + AT_B);
    bf16*         Wt   = (bf16*)(wsb + WT_B);
    float*        red  = (float*)(wsb + RED_B);
    unsigned int* ctr  = (unsigned int*)(wsb + CTR_B);
    int*          flag = (int*)(wsb + FLAG_B);

    hipMemsetAsync(wsb + RED_B, 0, 1024, stream);

    prep_at  <<<dim3(32, 32), 256, 0, stream>>>(A, At);
    w_mfma   <<<dim3(16, 16), 256, 0, stream>>>(At, B, Wt);
    bias_gemm<<<dim3(32, 8),  256, 0, stream>>>(x, UW, Ub, bias);
    f0_kernel<<<dim3(BSZ * OUT_DIM / 1024), 256, 0, stream>>>(bias, F, G, zh, zl);

    // f1 = relu(f0 @ W + bias), slot 1 (no err check)
    iter_mfma<false><<<dim3(32, 8), 256, 0, stream>>>(zh, zl, Wt, bias, F, G, out,
                                                      nullptr, nullptr, flag, 1, 0);

    for (int it = 2; it < MAX_ITER; ++it) {
        anderson_kernel<<<dim3(BSZ), 256, 0, stream>>>(F, G, zh, zl, flag, it);
        iter_mfma<true><<<dim3(32, 8), 256, 0, stream>>>(zh, zl, Wt, bias, F, G, out,
                                                         red, ctr, flag, it % M_AND, it);
    }
}

// Round 3
// 689.640 us; speedup vs baseline: 2.1191x; 1.1147x over previous
//
#include <hip/hip_runtime.h>
#include <hip/hip_bf16.h>
#include <math.h>

#define BSZ      512
#define IN_DIM   1024
#define OUT_DIM  2048
#define M_AND    5
#define LAM      1e-4f
#define TOL      1e-5f
#define MAX_ITER 50

typedef __bf16 bf16x8 __attribute__((ext_vector_type(8)));
typedef float  f32x4  __attribute__((ext_vector_type(4)));
typedef unsigned short u16x8 __attribute__((ext_vector_type(8)));
typedef __hip_bfloat16 bf16;

#define GAS __attribute__((address_space(1)))
#define LAS __attribute__((address_space(3)))

union BU { bf16 b; unsigned short u; };

__device__ __forceinline__ float bf2f(unsigned short u) {
    union { unsigned int i; float f; } c; c.i = (unsigned int)u << 16; return c.f;
}
__device__ __forceinline__ unsigned short f2bf(float f) {
    BU t; t.b = __float2bfloat16(f); return t.u;
}

// ---------------- workspace layout (byte offsets) ----------------
static constexpr size_t BIAS_B = 0;                                          // fp32 [512][2048]
static constexpr size_t F_B    = BIAS_B + (size_t)BSZ * OUT_DIM * 4;         // fp32 [512][5][2048]
static constexpr size_t G_B    = F_B    + (size_t)BSZ * M_AND * OUT_DIM * 4; // bf16 [512][5][2048]
static constexpr size_t ZH_B   = G_B    + (size_t)BSZ * M_AND * OUT_DIM * 2; // bf16 [512][2048]
static constexpr size_t ZL_B   = ZH_B   + (size_t)BSZ * OUT_DIM * 2;         // bf16 [512][2048]
static constexpr size_t XH_B   = ZL_B   + (size_t)BSZ * OUT_DIM * 2;         // bf16 [512][1024]
static constexpr size_t XL_B   = XH_B   + (size_t)BSZ * IN_DIM * 2;          // bf16 [512][1024]
static constexpr size_t UH_B   = XL_B   + (size_t)BSZ * IN_DIM * 2;          // bf16 [2048][1024]
static constexpr size_t UL_B   = UH_B   + (size_t)OUT_DIM * IN_DIM * 2;      // bf16 [2048][1024]
static constexpr size_t AT_B   = UL_B   + (size_t)OUT_DIM * IN_DIM * 2;      // bf16 [2048][2048] A^T
static constexpr size_t WT_B   = AT_B   + (size_t)OUT_DIM * OUT_DIM * 2;     // bf16 [2048][2048] W^T
static constexpr size_t RED_B  = WT_B   + (size_t)OUT_DIM * OUT_DIM * 2;     // fp32 [128]
static constexpr size_t CTR_B  = RED_B  + 512;                               // u32  [64]
static constexpr size_t FLAG_B = CTR_B  + 256;                               // int

// =================================================================
// Staging: global -> LDS, 16B/lane, tile pitch 128B (64 bf16 cols),
// T2 XOR swizzle via PRE-SWIZZLED global source (rule #21).
// =================================================================
template<int ROUNDS>
__device__ __forceinline__ void stage_tile(const void* __restrict__ g0, int row_bytes,
                                           void* l0, int tid)
{
    #pragma unroll
    for (int q = 0; q < ROUNDS; ++q) {
        const int D   = q * 4096 + tid * 16;
        const int r   = D >> 7;
        const int cb  = D & 127;
        const int scb = cb ^ ((r & 7) << 4);
        const char* gsrc = (const char*)g0 + (size_t)r * row_bytes + scb;
        char* ldst = (char*)l0 + q * 4096 + (tid >> 6) * 1024;
        __builtin_amdgcn_global_load_lds((const GAS void*)gsrc, (LAS void*)ldst, 16, 0, 0);
    }
}

__device__ __forceinline__ bf16x8 read_frag(const void* tile, int row, int cb)
{
    return *(const bf16x8*)((const char*)tile + row * 128 + (cb ^ ((row & 7) << 4)));
}

// =================================================================
// conv_hilo: fp32 -> bf16 hi/lo planes (4 elems/thread)
// =================================================================
__global__ __launch_bounds__(256)
void conv_hilo(const float* __restrict__ src, bf16* __restrict__ h, bf16* __restrict__ l)
{
    const size_t i4 = ((size_t)blockIdx.x * 256 + threadIdx.x) * 4;
    const float4 v = *(const float4*)&src[i4];
    const float vv[4] = {v.x, v.y, v.z, v.w};
    union { short4 s4; unsigned short u[4]; } ph, pl;
    #pragma unroll
    for (int j = 0; j < 4; ++j) {
        ph.u[j] = f2bf(vv[j]);
        pl.u[j] = f2bf(vv[j] - bf2f(ph.u[j]));
    }
    *(short4*)((char*)h + i4 * 2) = ph.s4;
    *(short4*)((char*)l + i4 * 2) = pl.s4;
}

// =================================================================
// prep_at: At[c][k] = bf16(A[k][c])
// =================================================================
__global__ __launch_bounds__(256)
void prep_at(const float* __restrict__ A, bf16* __restrict__ At)
{
    __shared__ float t[64][65];
    const int tid = threadIdx.x;
    const int k0 = blockIdx.y * 64, c0 = blockIdx.x * 64;
    const int cc = tid & 63, rr = tid >> 6;
    #pragma unroll
    for (int q = 0; q < 16; ++q)
        t[rr + 4 * q][cc] = A[(size_t)(k0 + rr + 4 * q) * OUT_DIM + c0 + cc];
    __syncthreads();
    #pragma unroll
    for (int q = 0; q < 16; ++q)
        At[(size_t)(c0 + rr + 4 * q) * OUT_DIM + k0 + cc] = __float2bfloat16(t[cc][rr + 4 * q]);
}

// =================================================================
// w_mfma (triangular): S = A^T A symmetric -> W + W^T = -2S.
// For lower-tri tile (ti>=tj) compute S[r][c], emit
//   Wt[c][r] = w  = B[c][r]-B[r][c]-S   and (ti!=tj)
//   Wt[r][c] = wm = -w - 2S
// 128x128 tile, 4 waves (2x2), BK=64, double-buffered.
// =================================================================
__global__ __launch_bounds__(256)
void w_mfma(const bf16* __restrict__ At, const float* __restrict__ Bm, bf16* __restrict__ Wt)
{
    __shared__ __align__(16) bf16 lds[2][2][128 * 64];
    const int tid = threadIdx.x;
    const int lane = tid & 63, wid = tid >> 6;
    const int wy = wid >> 1, wx = wid & 1;

    int bb = blockIdx.x;
    int ti = (int)((sqrtf(8.f * bb + 1.f) - 1.f) * 0.5f);
    while ((ti + 1) * (ti + 2) / 2 <= bb) ++ti;
    while (ti * (ti + 1) / 2 > bb) --ti;
    const int tj = bb - ti * (ti + 1) / 2;
    const int r0 = ti * 128, c0 = tj * 128;
    const bool diag = (ti == tj);

    f32x4 acc[4][4];
    #pragma unroll
    for (int i = 0; i < 4; ++i)
        #pragma unroll
        for (int j = 0; j < 4; ++j) acc[i][j] = 0;

    stage_tile<4>(At + (size_t)r0 * OUT_DIM, OUT_DIM * 2, lds[0][0], tid);
    stage_tile<4>(At + (size_t)c0 * OUT_DIM, OUT_DIM * 2, lds[0][1], tid);
    __syncthreads();
    int cur = 0;
    for (int t = 0; t < 32; ++t) {
        if (t + 1 < 32) {
            const int kk = (t + 1) * 64;
            stage_tile<4>(At + (size_t)r0 * OUT_DIM + kk, OUT_DIM * 2, lds[cur ^ 1][0], tid);
            stage_tile<4>(At + (size_t)c0 * OUT_DIM + kk, OUT_DIM * 2, lds[cur ^ 1][1], tid);
        }
        const bf16* Ta = lds[cur][0];
        const bf16* Tb = lds[cur][1];
        #pragma unroll
        for (int kf = 0; kf < 2; ++kf) {
            const int cb = kf * 64 + (lane >> 4) * 16;
            bf16x8 bfr[4];
            #pragma unroll
            for (int nj = 0; nj < 4; ++nj)
                bfr[nj] = read_frag(Tb, wx * 64 + nj * 16 + (lane & 15), cb);
            #pragma unroll
            for (int mi = 0; mi < 4; ++mi) {
                bf16x8 afr = read_frag(Ta, wy * 64 + mi * 16 + (lane & 15), cb);
                #pragma unroll
                for (int nj = 0; nj < 4; ++nj)
                    acc[mi][nj] = __builtin_amdgcn_mfma_f32_16x16x32_bf16(afr, bfr[nj], acc[mi][nj], 0, 0, 0);
            }
        }
        __syncthreads();
        cur ^= 1;
    }

    #pragma unroll
    for (int mi = 0; mi < 4; ++mi) {
        const int rb = r0 + wy * 64 + mi * 16 + (lane >> 4) * 4;
        #pragma unroll
        for (int nj = 0; nj < 4; ++nj) {
            const int c = c0 + wx * 64 + nj * 16 + (lane & 15);
            const float4 bc = *(const float4*)&Bm[(size_t)c * OUT_DIM + rb];
            const float bcv[4] = {bc.x, bc.y, bc.z, bc.w};
            union { short4 s4; unsigned short u[4]; } p;
            #pragma unroll
            for (int g = 0; g < 4; ++g) {
                const float a = acc[mi][nj][g];
                const float brc = Bm[(size_t)(rb + g) * OUT_DIM + c];
                const float w = bcv[g] - brc - a;
                p.u[g] = f2bf(w);
                if (!diag) {
                    const float wm = brc - bcv[g] - a;
                    *((unsigned short*)Wt + (size_t)(rb + g) * OUT_DIM + c) = f2bf(wm);
                }
            }
            *(short4*)((char*)Wt + ((size_t)c * OUT_DIM + rb) * 2) = p.s4;
        }
    }
}

// =================================================================
// bias_mfma: bias = x @ UW^T + Ub via 3-pass hi/lo MFMA, fused f0:
//   f0 = relu(bias); F0 = G0 = f0; (zh,zl) = split(f0)
// 64x64 tile, grid (32,8), 4 waves (2x2), BK=64, double-buffered.
// =================================================================
__global__ __launch_bounds__(256)
void bias_mfma(const bf16* __restrict__ xh, const bf16* __restrict__ xl,
               const bf16* __restrict__ uh, const bf16* __restrict__ ul,
               const float* __restrict__ Ub, float* __restrict__ bias,
               float* __restrict__ F, unsigned short* __restrict__ G,
               unsigned short* __restrict__ zh, unsigned short* __restrict__ zl)
{
    __shared__ __align__(16) bf16 lds[2][4][64 * 64];
    const int tid = threadIdx.x;
    const int lane = tid & 63, wid = tid >> 6;
    const int wy = wid >> 1, wx = wid & 1;
    const int m0 = blockIdx.y * 64, n0 = blockIdx.x * 64;

    f32x4 acc[2][2];
    #pragma unroll
    for (int i = 0; i < 2; ++i)
        #pragma unroll
        for (int j = 0; j < 2; ++j) acc[i][j] = 0;

    stage_tile<2>(xh + (size_t)m0 * IN_DIM, IN_DIM * 2, lds[0][0], tid);
    stage_tile<2>(xl + (size_t)m0 * IN_DIM, IN_DIM * 2, lds[0][1], tid);
    stage_tile<2>(uh + (size_t)n0 * IN_DIM, IN_DIM * 2, lds[0][2], tid);
    stage_tile<2>(ul + (size_t)n0 * IN_DIM, IN_DIM * 2, lds[0][3], tid);
    __syncthreads();
    int cur = 0;
    for (int t = 0; t < 16; ++t) {
        if (t + 1 < 16) {
            const int kk = (t + 1) * 64;
            stage_tile<2>(xh + (size_t)m0 * IN_DIM + kk, IN_DIM * 2, lds[cur ^ 1][0], tid);
            stage_tile<2>(xl + (size_t)m0 * IN_DIM + kk, IN_DIM * 2, lds[cur ^ 1][1], tid);
            stage_tile<2>(uh + (size_t)n0 * IN_DIM + kk, IN_DIM * 2, lds[cur ^ 1][2], tid);
            stage_tile<2>(ul + (size_t)n0 * IN_DIM + kk, IN_DIM * 2, lds[cur ^ 1][3], tid);
        }
        const bf16* Txh = lds[cur][0];
        const bf16* Txl = lds[cur][1];
        const bf16* Tuh = lds[cur][2];
        const bf16* Tul = lds[cur][3];
        #pragma unroll
        for (int kf = 0; kf < 2; ++kf) {
            const int cb = kf * 64 + (lane >> 4) * 16;
            bf16x8 bh[2], bl[2];
            #pragma unroll
            for (int nj = 0; nj < 2; ++nj) {
                const int br = wx * 32 + nj * 16 + (lane & 15);
                bh[nj] = read_frag(Tuh, br, cb);
                bl[nj] = read_frag(Tul, br, cb);
            }
            #pragma unroll
            for (int mi = 0; mi < 2; ++mi) {
                const int ar = wy * 32 + mi * 16 + (lane & 15);
                bf16x8 ah = read_frag(Txh, ar, cb);
                bf16x8 al = read_frag(Txl, ar, cb);
                #pragma unroll
                for (int nj = 0; nj < 2; ++nj) {
                    acc[mi][nj] = __builtin_amdgcn_mfma_f32_16x16x32_bf16(ah, bh[nj], acc[mi][nj], 0, 0, 0);
                    acc[mi][nj] = __builtin_amdgcn_mfma_f32_16x16x32_bf16(ah, bl[nj], acc[mi][nj], 0, 0, 0);
                    acc[mi][nj] = __builtin_amdgcn_mfma_f32_16x16x32_bf16(al, bh[nj], acc[mi][nj], 0, 0, 0);
                }
            }
        }
        __syncthreads();
        cur ^= 1;
    }

    #pragma unroll
    for (int mi = 0; mi < 2; ++mi) {
        const int mb = m0 + wy * 32 + mi * 16 + (lane >> 4) * 4;
        #pragma unroll
        for (int nj = 0; nj < 2; ++nj) {
            const int n = n0 + wx * 32 + nj * 16 + (lane & 15);
            const float ub = Ub[n];
            #pragma unroll
            for (int g = 0; g < 4; ++g) {
                const int m = mb + g;
                const size_t idx = (size_t)m * OUT_DIM + n;
                const float v = acc[mi][nj][g] + ub;
                bias[idx] = v;
                const float f = fmaxf(v, 0.f);
                F[((size_t)m * M_AND + 0) * OUT_DIM + n] = f;
                G[((size_t)m * M_AND + 0) * OUT_DIM + n] = f2bf(f);
                const unsigned short h = f2bf(f);
                zh[idx] = h;
                zl[idx] = f2bf(f - bf2f(h));
            }
        }
    }
}

// =================================================================
// iter_mfma: zo = relu((zh+zl) @ W + bias), split-z exact 2-pass.
// Epilogue: F[slot]=zo (fp32), G[slot]=bf16(zo-z), out=zo, err.
// =================================================================
template<bool DO_ERR>
__global__ __launch_bounds__(256)
void iter_mfma(const unsigned short* __restrict__ zh, const unsigned short* __restrict__ zl,
               const bf16* __restrict__ Wt, const float* __restrict__ bias,
               float* __restrict__ F, unsigned short* __restrict__ G, float* __restrict__ out,
               float* red, unsigned int* ctr, int* flag, int slot, int it)
{
    if (((volatile int*)flag)[0]) return;
    __shared__ __align__(16) bf16 lds[2][3][64 * 64];
    const int tid = threadIdx.x;
    const int lane = tid & 63, wid = tid >> 6;
    const int wy = wid >> 1, wx = wid & 1;
    const int m0 = blockIdx.y * 64, n0 = blockIdx.x * 64;

    f32x4 acc[2][2];
    #pragma unroll
    for (int i = 0; i < 2; ++i)
        #pragma unroll
        for (int j = 0; j < 2; ++j) acc[i][j] = 0;

    stage_tile<2>(zh + (size_t)m0 * OUT_DIM, OUT_DIM * 2, lds[0][0], tid);
    stage_tile<2>(zl + (size_t)m0 * OUT_DIM, OUT_DIM * 2, lds[0][1], tid);
    stage_tile<2>(Wt + (size_t)n0 * OUT_DIM, OUT_DIM * 2, lds[0][2], tid);
    __syncthreads();
    int cur = 0;
    for (int t = 0; t < 32; ++t) {
        if (t + 1 < 32) {
            const int kk = (t + 1) * 64;
            stage_tile<2>(zh + (size_t)m0 * OUT_DIM + kk, OUT_DIM * 2, lds[cur ^ 1][0], tid);
            stage_tile<2>(zl + (size_t)m0 * OUT_DIM + kk, OUT_DIM * 2, lds[cur ^ 1][1], tid);
            stage_tile<2>(Wt + (size_t)n0 * OUT_DIM + kk, OUT_DIM * 2, lds[cur ^ 1][2], tid);
        }
        const bf16* Th = lds[cur][0];
        const bf16* Tl = lds[cur][1];
        const bf16* Tw = lds[cur][2];
        #pragma unroll
        for (int kf = 0; kf < 2; ++kf) {
            const int cb = kf * 64 + (lane >> 4) * 16;
            bf16x8 bfr[2];
            #pragma unroll
            for (int nj = 0; nj < 2; ++nj)
                bfr[nj] = read_frag(Tw, wx * 32 + nj * 16 + (lane & 15), cb);
            #pragma unroll
            for (int mi = 0; mi < 2; ++mi) {
                const int rrow = wy * 32 + mi * 16 + (lane & 15);
                bf16x8 ah = read_frag(Th, rrow, cb);
                bf16x8 al = read_frag(Tl, rrow, cb);
                #pragma unroll
                for (int nj = 0; nj < 2; ++nj) {
                    acc[mi][nj] = __builtin_amdgcn_mfma_f32_16x16x32_bf16(ah, bfr[nj], acc[mi][nj], 0, 0, 0);
                    acc[mi][nj] = __builtin_amdgcn_mfma_f32_16x16x32_bf16(al, bfr[nj], acc[mi][nj], 0, 0, 0);
                }
            }
        }
        __syncthreads();
        cur ^= 1;
    }

    float lnum = 0.f, lden = 0.f;
    #pragma unroll
    for (int mi = 0; mi < 2; ++mi) {
        const int mb = m0 + wy * 32 + mi * 16 + (lane >> 4) * 4;
        #pragma unroll
        for (int nj = 0; nj < 2; ++nj) {
            const int n = n0 + wx * 32 + nj * 16 + (lane & 15);
            #pragma unroll
            for (int g = 0; g < 4; ++g) {
                const int m = mb + g;
                const size_t idx = (size_t)m * OUT_DIM + n;
                float v = acc[mi][nj][g] + bias[idx];
                v = fmaxf(v, 0.f);
                const float zc = bf2f(zh[idx]) + bf2f(zl[idx]);
                const float gg = v - zc;
                F[((size_t)m * M_AND + slot) * OUT_DIM + n] = v;
                G[((size_t)m * M_AND + slot) * OUT_DIM + n] = f2bf(gg);
                out[idx] = v;
                if (DO_ERR) { lnum += gg * gg; lden += v * v; }
            }
        }
    }

    if (DO_ERR) {
        #pragma unroll
        for (int off = 32; off; off >>= 1) {
            lnum += __shfl_down(lnum, off);
            lden += __shfl_down(lden, off);
        }
        __shared__ float swn[4], swd[4];
        if ((tid & 63) == 0) { swn[tid >> 6] = lnum; swd[tid >> 6] = lden; }
        __syncthreads();
        if (tid == 0) {
            atomicAdd(&red[2 * it],     swn[0] + swn[1] + swn[2] + swn[3]);
            atomicAdd(&red[2 * it + 1], swd[0] + swd[1] + swd[2] + swd[3]);
            __threadfence();
            const unsigned int done = atomicAdd(&ctr[it], 1u);
            if (done == gridDim.x * gridDim.y - 1) {
                const float num2 = ((volatile float*)red)[2 * it];
                const float den2 = ((volatile float*)red)[2 * it + 1];
                if (sqrtf(num2) <= TOL * (1e-6f + sqrtf(den2)))
                    ((volatile int*)flag)[0] = 1;
            }
        }
    }
}

// =================================================================
// anderson: GGt from bf16 G (vector loads), Cholesky, alpha,
// z_new = sum alpha_m F[:,m] (float4 loads) -> (zh,zl).
// One block/row, thread t owns contiguous elements [8t..8t+7].
// =================================================================
__global__ __launch_bounds__(256)
void anderson_kernel(const float* __restrict__ F, const unsigned short* __restrict__ G,
                     unsigned short* __restrict__ zh, unsigned short* __restrict__ zl,
                     int* flag, int it)
{
    if (((volatile int*)flag)[0]) return;
    const int b = blockIdx.x;
    const int tid = threadIdx.x;
    const int n = (it < M_AND) ? it : M_AND;
    const unsigned short* Gb = G + (size_t)b * M_AND * OUT_DIM;
    const float* Fb = F + (size_t)b * M_AND * OUT_DIM;

    float g[M_AND][8];
    #pragma unroll
    for (int m = 0; m < M_AND; ++m) {
        if (m < n) {
            const u16x8 gv = *(const u16x8*)(Gb + (size_t)m * OUT_DIM + tid * 8);
            #pragma unroll
            for (int q = 0; q < 8; ++q) g[m][q] = bf2f(gv[q]);
        } else {
            #pragma unroll
            for (int q = 0; q < 8; ++q) g[m][q] = 0.f;
        }
    }

    float dots[15];
    {
        int p = 0;
        #pragma unroll
        for (int i = 0; i < M_AND; ++i)
            #pragma unroll
            for (int j = i; j < M_AND; ++j) {
                float s = 0.f;
                #pragma unroll
                for (int q = 0; q < 8; ++q) s += g[i][q] * g[j][q];
                dots[p++] = s;
            }
    }

    __shared__ float sred[15][4];
    #pragma unroll
    for (int p = 0; p < 15; ++p) {
        float v = dots[p];
        #pragma unroll
        for (int off = 32; off; off >>= 1) v += __shfl_down(v, off);
        if ((tid & 63) == 0) sred[p][tid >> 6] = v;
    }
    __syncthreads();

    __shared__ float s_alpha[M_AND];
    if (tid == 0) {
        float GGm[M_AND][M_AND];
        int p = 0;
        for (int i = 0; i < M_AND; ++i)
            for (int j = i; j < M_AND; ++j) {
                const float v = sred[p][0] + sred[p][1] + sred[p][2] + sred[p][3];
                GGm[i][j] = v; GGm[j][i] = v; ++p;
            }
        float fro = 0.f;
        for (int i = 0; i < M_AND; ++i)
            for (int j = 0; j < M_AND; ++j) fro += GGm[i][j] * GGm[i][j];
        const float inv = 1.f / (sqrtf(fro) + 1e-6f);

        float Mm[M_AND][M_AND];
        for (int i = 0; i < n; ++i)
            for (int j = 0; j < n; ++j)
                Mm[i][j] = GGm[i][j] * inv + (i == j ? LAM : 0.f);

        float L[M_AND][M_AND];
        for (int i = 0; i < n; ++i)
            for (int j = 0; j <= i; ++j) {
                float s = Mm[i][j];
                for (int k = 0; k < j; ++k) s -= L[i][k] * L[j][k];
                L[i][j] = (i == j) ? sqrtf(fmaxf(s, 1e-20f)) : s / L[j][j];
            }
        float y[M_AND], u[M_AND];
        for (int i = 0; i < n; ++i) {
            float s = 1.f;
            for (int k = 0; k < i; ++k) s -= L[i][k] * y[k];
            y[i] = s / L[i][i];
        }
        for (int i = n - 1; i >= 0; --i) {
            float s = y[i];
            for (int k = i + 1; k < n; ++k) s -= L[k][i] * u[k];
            u[i] = s / L[i][i];
        }
        float su = 0.f;
        for (int i = 0; i < n; ++i) su += u[i];
        const float isu = 1.f / su;
        for (int m = 0; m < M_AND; ++m) s_alpha[m] = (m < n) ? u[m] * isu : 0.f;
    }
    __syncthreads();

    float z[8] = {};
    #pragma unroll
    for (int m = 0; m < M_AND; ++m) {
        if (m < n) {
            const float a = s_alpha[m];
            const float4 fa = *(const float4*)(Fb + (size_t)m * OUT_DIM + tid * 8);
            const float4 fb2 = *(const float4*)(Fb + (size_t)m * OUT_DIM + tid * 8 + 4);
            z[0] += a * fa.x;  z[1] += a * fa.y;  z[2] += a * fa.z;  z[3] += a * fa.w;
            z[4] += a * fb2.x; z[5] += a * fb2.y; z[6] += a * fb2.z; z[7] += a * fb2.w;
        }
    }
    u16x8 hv, lv;
    #pragma unroll
    for (int q = 0; q < 8; ++q) {
        const unsigned short h = f2bf(z[q]);
        hv[q] = h;
        lv[q] = f2bf(z[q] - bf2f(h));
    }
    *(u16x8*)(zh + (size_t)b * OUT_DIM + tid * 8) = hv;
    *(u16x8*)(zl + (size_t)b * OUT_DIM + tid * 8) = lv;
}

// =================================================================
extern "C" void kernel_launch(void* const* d_in, const int* in_sizes, int n_in,
                              void* d_out, int out_size, void* d_ws, size_t ws_size,
                              hipStream_t stream)
{
    const float* x  = (const float*)d_in[0];
    const float* A  = (const float*)d_in[1];
    const float* B  = (const float*)d_in[2];
    const float* UW = (const float*)d_in[3];
    const float* Ub = (const float*)d_in[4];
    float* out = (float*)d_out;
    char*  wsb = (char*)d_ws;

    float*          bias = (float*)(wsb + BIAS_B);
    float*          F    = (float*)(wsb + F_B);
    unsigned short* G    = (unsigned short*)(wsb + G_B);
    unsigned short* zh   = (unsigned short*)(wsb + ZH_B);
    unsigned short* zl   = (unsigned short*)(wsb + ZL_B);
    bf16*           xh   = (bf16*)(wsb + XH_B);
    bf16*           xl   = (bf16*)(wsb + XL_B);
    bf16*           uh   = (bf16*)(wsb + UH_B);
    bf16*           ul   = (bf16*)(wsb + UL_B);
    bf16*           At   = (bf16*)(wsb + AT_B);
    bf16*           Wt   = (bf16*)(wsb + WT_B);
    float*          red  = (float*)(wsb + RED_B);
    unsigned int*   ctr  = (unsigned int*)(wsb + CTR_B);
    int*            flag = (int*)(wsb + FLAG_B);

    hipMemsetAsync(wsb + RED_B, 0, 1024, stream);

    conv_hilo<<<dim3(BSZ * IN_DIM / 1024),     256, 0, stream>>>(x,  xh, xl);
    conv_hilo<<<dim3(OUT_DIM * IN_DIM / 1024), 256, 0, stream>>>(UW, uh, ul);
    prep_at  <<<dim3(32, 32), 256, 0, stream>>>(A, At);
    w_mfma   <<<dim3(136), 256, 0, stream>>>(At, B, Wt);
    bias_mfma<<<dim3(32, 8), 256, 0, stream>>>(xh, xl, uh, ul, Ub, bias, F, G, zh, zl);

    // f1 = relu(f0 @ W + bias), slot 1 (no err check)
    iter_mfma<false><<<dim3(32, 8), 256, 0, stream>>>(zh, zl, Wt, bias, F, G, out,
                                                      nullptr, nullptr, flag, 1, 0);

    for (int it = 2; it < MAX_ITER; ++it) {
        anderson_kernel<<<dim3(BSZ), 256, 0, stream>>>(F, G, zh, zl, flag, it);
        iter_mfma<true><<<dim3(32, 8), 256, 0, stream>>>(zh, zl, Wt, bias, F, G, out,
                                                         red, ctr, flag, it % M_AND, it);
    }
}